// Round 10
// baseline (468.358 us; speedup 1.0000x reference)
//
#include <hip/hip_runtime.h>
#include <hip/hip_bf16.h>
#include <math.h>

// Problem constants
#define DDIM   300
#define PFN    12
#define LFN    8
#define ICH    21      // PF + LF + 1
#define TPB    256     // 4 waves/block; 4 lanes per sample
#define SPB    64      // samples per block
#define SLOT_DW 99     // per-sample feature slot: 9 positions * 11 dwords
#define W1PAD  2640    // 20 oc * 11 icp * 12 (9 taps + 3 pad) bf16-pair dw (10560 B)
#define W2N    2400    // 30*20*4  conv2 weights fp32 (9600 B)
#define FW1P   2400    // 120 rows * 20 dw (19 real + 1 pad)   (9600 B)
#define FW2P   5376    // 84 rows * 4 chunks * 16 dw (15 real + 1 pad) (21504 B)
#define BIASN  339     // b1(20)+b2(30)+fb1(120)+fb2(84)+fw3(84)+fb3(1)
// bias[] layout offsets:
#define OB1    0
#define OB2    20
#define OFB1   50
#define OFB2   170
#define OFW3   254
#define OFB3   338

__device__ __forceinline__ float lrelu(float v) { return v > 0.0f ? v : 0.2f * v; }

__device__ __forceinline__ unsigned int pack2(float a, float b) {
    union { __hip_bfloat162 h; unsigned int u; } cv;
    cv.h.x = __float2bfloat16(a);
    cv.h.y = __float2bfloat16(b);
    return cv.u;
}
__device__ __forceinline__ float bflo(unsigned int u) {
    union { unsigned int i; float f; } c; c.i = u << 16; return c.f;
}
__device__ __forceinline__ float bfhi(unsigned int u) {
    union { unsigned int i; float f; } c; c.i = u & 0xffff0000u; return c.f;
}

// Packed bf16 dot-2 with f32 accumulate: d = a.lo*b.lo + a.hi*b.hi + c.
__device__ __forceinline__ float dot2bf(unsigned int a, unsigned int b, float c) {
    float d;
    asm("v_dot2_f32_bf16 %0, %1, %2, %3" : "=v"(d) : "v"(a), "v"(b), "v"(c));
    return d;
}

// 3x3 conv (pad=1) on a 3x3 grid: accumulate one packed ic-PAIR into 9 outputs.
__device__ __forceinline__ void conv_acc2(float o[9], const unsigned int w[9],
                                          const unsigned int fv[9]) {
#pragma unroll
    for (int t = 0; t < 9; ++t) {
        const int ky = t / 3 - 1, kx = t % 3 - 1;
        const unsigned int wv = w[t];
#pragma unroll
        for (int y = 0; y < 3; ++y) {
            const int iy = y + ky;
            if (iy < 0 || iy > 2) continue;
#pragma unroll
            for (int x = 0; x < 3; ++x) {
                const int ix = x + kx;
                if (ix < 0 || ix > 2) continue;
                o[y * 3 + x] = dot2bf(wv, fv[iy * 3 + ix], o[y * 3 + x]);
            }
        }
    }
}

// r9: dot2 cut the kernel to ~138us. Audit: DS-read ISSUE is now the widest
// pipe (~2600 b32 ds_reads/wave, ~75% of CU DS-pipe cycles; LDS *bandwidth*
// only ~16%). This round: pad weight layouts so every FC/conv1 weight read is
// ds_read_b128 (DS instrs ~2600 -> ~900). Zero numeric change (same values,
// new addresses) -> absmax must stay exactly 0.00390625.
__launch_bounds__(TPB, 2)
__global__ void disc_kernel(
    const int* __restrict__ state, const int* __restrict__ des,
    const int* __restrict__ act,
    const int* __restrict__ asp_g,   // action_state_pad (S,9)
    const int* __restrict__ pmp_g,   // policy_mask_pad  (S,9)
    const float* __restrict__ path_feature,  // (S,D,12)
    const float* __restrict__ link_feature,  // (S,8)
    const float* __restrict__ w1, const float* __restrict__ b1,   // conv1 (20,21,3,3)
    const float* __restrict__ w2, const float* __restrict__ b2,   // conv2 (30,20,2,2)
    const float* __restrict__ fw1, const float* __restrict__ fb1, // (120,38)
    const float* __restrict__ fw2, const float* __restrict__ fb2, // (84,120)
    const float* __restrict__ fw3, const float* __restrict__ fb3, // (1,84)
    float* __restrict__ out, int n)
{
    __shared__ __align__(16) unsigned int w1p[W1PAD]; // 10560 B bf16 ic-pairs, 12-dw tap rows
    __shared__ __align__(16) float w2s[W2N];          //  9600 B fp32
    __shared__ __align__(16) unsigned int fw1h[FW1P]; //  9600 B bf16x2, 20-dw rows
    __shared__ __align__(16) unsigned int fw2h[FW2P]; // 21504 B bf16x2, 16-dw lane chunks
    __shared__ float bias[BIASN];                     //  1356 B fp32
    __shared__ unsigned int feat[SPB * SLOT_DW];      // 25344 B  => 77964 B total

    const int tid = threadIdx.x;

    // ---- Stage all weights/biases to LDS once per block.
    {
        // conv1: w1p[oc][icp][t(12)] = pack2(w1[oc][2icp][t], w1[oc][2icp+1][t]);
        // icp==10 pairs ic20 with zero; t>=9 is pad.
        for (int i = tid; i < W1PAD; i += TPB) {
            const int oc = i / 132, r = i % 132, icp = r / 12, t = r % 12;
            unsigned int v = 0u;
            if (t < 9) {
                const float lo = w1[(oc * ICH + 2 * icp) * 9 + t];
                const float hi = (icp < 10) ? w1[(oc * ICH + 2 * icp + 1) * 9 + t] : 0.0f;
                v = pack2(lo, hi);
            }
            w1p[i] = v;
        }
        const float4* s2 = (const float4*)w2;  float4* d2 = (float4*)w2s;
        for (int i = tid; i < W2N / 4; i += TPB) d2[i] = s2[i];
        // fc1: fw1h[j][0..18] = packed pairs of fw1 row j (38 f32 = 19 pairs); [19]=pad
        for (int i = tid; i < FW1P; i += TPB) {
            const int row = i / 20, col = i % 20;
            unsigned int v = 0u;
            if (col < 19) v = pack2(fw1[row * 38 + 2 * col], fw1[row * 38 + 2 * col + 1]);
            fw1h[i] = v;
        }
        // fc2: fw2h[i][chunk(4)][m(16)] = pack2(fw2[i][chunk*30+2m], [..+1]); m==15 pad
        for (int i = tid; i < FW2P; i += TPB) {
            const int row = i / 64, c = i % 64, ch = c / 16, m = c % 16;
            unsigned int v = 0u;
            if (m < 15) v = pack2(fw2[row * 120 + ch * 30 + 2 * m],
                                  fw2[row * 120 + ch * 30 + 2 * m + 1]);
            fw2h[i] = v;
        }
        for (int i = tid; i < BIASN; i += TPB) {
            float v;
            if      (i < OB2)  v = b1[i];
            else if (i < OFB1) v = b2[i - OB2];
            else if (i < OFB2) v = fb1[i - OFB1];
            else if (i < OFW3) v = fb2[i - OFB2];
            else if (i < OFB3) v = fw3[i - OFW3];
            else               v = fb3[0];
            bias[i] = v;
        }
    }
    __syncthreads();

    const int lane4  = tid & 3;       // lane within sample quad
    const int lsamp  = tid >> 2;      // sample within block
    const int sample = blockIdx.x * SPB + lsamp;
    if (sample >= n) return;

    const int s  = state[sample];
    const int d  = des[sample];
    const int ai = act[sample];

    const int* asp = asp_g + s * 9;
    const int* pmp = pmp_g + s * 9;
    unsigned int* fslot = feat + lsamp * SLOT_DW;

    // ---- Cooperative gather: lane k handles positions k, k+4, k+8.
    // NEW_INDEX packed as nibbles: p -> {7,0,1,6,8,2,5,4,3}
#pragma unroll
    for (int t = 0; t < 3; ++t) {
        const int p = lane4 + 4 * t;
        if (p < 9) {
            const int a  = (int)((0x345286107ULL >> (4 * p)) & 0xF);
            const int na = asp[a];
            const float m = (float)pmp[a];
            const float4* pf = (const float4*)(path_feature + (na * DDIM + d) * PFN);
            const float4 v0 = pf[0], v1 = pf[1], v2 = pf[2];
            const float4* lf = (const float4*)(link_feature + na * LFN);
            const float4 u0 = lf[0], u1 = lf[1];
            unsigned int* dst = fslot + p * 11;   // 22 bf16 per position (dword aligned)
            dst[0] = pack2(v0.x, v0.y); dst[1] = pack2(v0.z, v0.w);
            dst[2] = pack2(v1.x, v1.y); dst[3] = pack2(v1.z, v1.w);
            dst[4] = pack2(v2.x, v2.y); dst[5] = pack2(v2.z, v2.w);
            dst[6] = pack2(u0.x, u0.y); dst[7] = pack2(u0.z, u0.w);
            dst[8] = pack2(u1.x, u1.y); dst[9] = pack2(u1.z, u1.w);
            dst[10] = pack2(m, 0.0f);             // channel 20 = mask, high half = pad
        }
    }
    // Quad writes its own slot (same wave): drain ds_writes before reads.
    asm volatile("s_waitcnt lgkmcnt(0)" ::: "memory");

    // ---- conv1: lane k computes output channels [5k, 5k+5) via dot2.
    const int oc0 = lane4 * 5;
    float o[5][9];
#pragma unroll
    for (int c = 0; c < 5; ++c) {
        const float bb = bias[OB1 + oc0 + c];
#pragma unroll
        for (int q = 0; q < 9; ++q) o[c][q] = bb;
    }

#pragma unroll 1
    for (int icp = 0; icp < 11; ++icp) {
        unsigned int fwd[9];
#pragma unroll
        for (int q = 0; q < 9; ++q) fwd[q] = fslot[q * 11 + icp];
#pragma unroll
        for (int c = 0; c < 5; ++c) {
            const unsigned int* wrow = w1p + ((oc0 + c) * 11 + icp) * 12; // 48B-aligned
            const uint4* w4 = (const uint4*)wrow;
            const uint4 wa = w4[0], wb = w4[1];
            const unsigned int w8 = wrow[8];
            const unsigned int wt[9] = {wa.x, wa.y, wa.z, wa.w, wb.x, wb.y, wb.z, wb.w, w8};
            conv_acc2(o[c], wt, fwd);
        }
    }

    // ---- lrelu + 2x2 maxpool (stride 1) on local 5 channels
    float pooled[5][4];
#pragma unroll
    for (int c = 0; c < 5; ++c) {
        float v[9];
#pragma unroll
        for (int q = 0; q < 9; ++q) v[q] = lrelu(o[c][q]);
        pooled[c][0] = fmaxf(fmaxf(v[0], v[1]), fmaxf(v[3], v[4]));
        pooled[c][1] = fmaxf(fmaxf(v[1], v[2]), fmaxf(v[4], v[5]));
        pooled[c][2] = fmaxf(fmaxf(v[3], v[4]), fmaxf(v[6], v[7]));
        pooled[c][3] = fmaxf(fmaxf(v[4], v[5]), fmaxf(v[7], v[8]));
    }

    // ---- conv2 (2x2 VALID): per-lane partial over its 5 oc (f32 b128 reads),
    // quad butterfly reduce. FULLY unrolled (rule #20: x30 static writes).
    float x30[30];
#pragma unroll
    for (int j = 0; j < 30; ++j) {
        const float4* wr = (const float4*)(w2s + j * 80 + oc0 * 4);  // 16B aligned
        float acc = 0.0f;
#pragma unroll
        for (int c = 0; c < 5; ++c) {
            const float4 wv = wr[c];
            acc = fmaf(wv.x, pooled[c][0], acc);
            acc = fmaf(wv.y, pooled[c][1], acc);
            acc = fmaf(wv.z, pooled[c][2], acc);
            acc = fmaf(wv.w, pooled[c][3], acc);
        }
        acc += __shfl_xor(acc, 1, 64);
        acc += __shfl_xor(acc, 2, 64);
        x30[j] = lrelu(acc + bias[OB2 + j]);
    }

    // Pack x30 once to bf16 pairs for the dot2 FC path.
    unsigned int xp[15];
#pragma unroll
    for (int m = 0; m < 15; ++m) xp[m] = pack2(x30[2 * m], x30[2 * m + 1]);

    // ---- fc1 (38->120): lane k computes rows [30k, 30k+30) via dot2,
    // weights as 4x ds_read_b128 per row (20-dw padded rows).
    float h1[30];
    const int j0 = lane4 * 30;
    const int ohd   = (30 + ai) >> 1;  // one-hot dword within row (15..18)
    const int ohodd = (30 + ai) & 1;   // which bf16 half
#pragma unroll
    for (int jj = 0; jj < 30; ++jj) {
        const unsigned int* wr = fw1h + (j0 + jj) * 20;        // 80B-aligned
        const uint4* w4 = (const uint4*)wr;
        const uint4 a0 = w4[0], a1 = w4[1], a2 = w4[2];
        const unsigned int w12 = wr[12], w13 = wr[13], w14 = wr[14];
        const unsigned int uoh = wr[ohd];                      // dynamic b32
        float acc = bias[OFB1 + j0 + jj] + (ohodd ? bfhi(uoh) : bflo(uoh));
        const unsigned int wv[15] = {a0.x, a0.y, a0.z, a0.w, a1.x, a1.y, a1.z, a1.w,
                                     a2.x, a2.y, a2.z, a2.w, w12, w13, w14};
#pragma unroll
        for (int m = 0; m < 15; ++m)
            acc = dot2bf(wv[m], xp[m], acc);
        h1[jj] = lrelu(acc);
    }

    // Pack h1 once to bf16 pairs.
    unsigned int hp[15];
#pragma unroll
    for (int m = 0; m < 15; ++m) hp[m] = pack2(h1[2 * m], h1[2 * m + 1]);

    // ---- fc2 (120->84) + fc3 (84->1): 4x ds_read_b128 per output (16-dw
    // lane chunks), dot2 partial, butterfly reduce, fold into fc3.
    float z = bias[OFB3];
#pragma unroll 2
    for (int i = 0; i < 84; ++i) {
        const uint4* w4 = (const uint4*)(fw2h + i * 64 + lane4 * 16);  // 64B-aligned
        const uint4 a0 = w4[0], a1 = w4[1], a2 = w4[2], a3 = w4[3];
        const unsigned int wv[15] = {a0.x, a0.y, a0.z, a0.w, a1.x, a1.y, a1.z, a1.w,
                                     a2.x, a2.y, a2.z, a2.w, a3.x, a3.y, a3.z};
        float a = 0.0f;
#pragma unroll
        for (int m = 0; m < 15; ++m)
            a = dot2bf(wv[m], hp[m], a);
        a += __shfl_xor(a, 1, 64);
        a += __shfl_xor(a, 2, 64);
        z = fmaf(bias[OFW3 + i], lrelu(a + bias[OFB2 + i]), z);
    }

    if (lane4 == 0)
        out[sample] = 1.0f / (1.0f + __expf(-z));
}

extern "C" void kernel_launch(void* const* d_in, const int* in_sizes, int n_in,
                              void* d_out, int out_size, void* d_ws, size_t ws_size,
                              hipStream_t stream) {
    const int*   state = (const int*)d_in[0];
    const int*   des   = (const int*)d_in[1];
    const int*   act   = (const int*)d_in[2];
    const int*   asp   = (const int*)d_in[3];
    const int*   pmp   = (const int*)d_in[4];
    const float* pathf = (const float*)d_in[5];
    const float* linkf = (const float*)d_in[6];
    const float* w1    = (const float*)d_in[7];
    const float* b1    = (const float*)d_in[8];
    const float* w2    = (const float*)d_in[9];
    const float* b2    = (const float*)d_in[10];
    const float* fw1   = (const float*)d_in[11];
    const float* fb1   = (const float*)d_in[12];
    const float* fw2   = (const float*)d_in[13];
    const float* fb2   = (const float*)d_in[14];
    const float* fw3   = (const float*)d_in[15];
    const float* fb3   = (const float*)d_in[16];

    const int n = in_sizes[0];
    dim3 grid((n + SPB - 1) / SPB), block(TPB);
    hipLaunchKernelGGL(disc_kernel, grid, block, 0, stream,
                       state, des, act, asp, pmp, pathf, linkf,
                       w1, b1, w2, b2, fw1, fb1, fw2, fb2, fw3, fb3,
                       (float*)d_out, n);
}